// Round 1
// baseline (730.784 us; speedup 1.0000x reference)
//
#include <hip/hip_runtime.h>

#define SLEN 2048
#define BATCH 32
#define HDIM 512
#define KDIM 1024   // 2H

typedef _Float16 f16x8 __attribute__((ext_vector_type(8)));
typedef _Float16 f16x4 __attribute__((ext_vector_type(4)));
typedef float f32x4 __attribute__((ext_vector_type(4)));

__device__ __forceinline__ void gload16(const void* g, void* l) {
  __builtin_amdgcn_global_load_lds(
      (const __attribute__((address_space(1))) unsigned int*)g,
      (__attribute__((address_space(3))) unsigned int*)l, 16, 0, 0);
}

__device__ __forceinline__ float fast_tanh(float x) {
  // 1 - 2/(exp(2x)+1); exact at +/-inf saturation, ~1e-6 rel err
  float e = __expf(2.0f * x);
  return 1.0f - 2.0f * __builtin_amdgcn_rcpf(e + 1.0f);
}

// ---- Convert W2 = attn_w[:, 1024:2048] to f16, row-major [512][1024] ----
__global__ __launch_bounds__(256) void convB_k(const float* __restrict__ attn_w,
                                               _Float16* __restrict__ Bt) {
  int t = blockIdx.x * 256 + threadIdx.x;   // 131072 threads, 4 elems each
  int h = t >> 8;                           // 256 float4 per row
  int c = t & 255;
  float4 x = *(const float4*)(attn_w + (size_t)h * 2048 + 1024 + c * 4);
  f16x4 y = {(_Float16)x.x, (_Float16)x.y, (_Float16)x.z, (_Float16)x.w};
  *(f16x4*)(Bt + (size_t)h * 1024 + c * 4) = y;
}

// ---- s1[b][h] = hidden[b,:]·attn_w[h, 0:1024] + attn_b[h]  (fp32) ----
__global__ __launch_bounds__(256) void s1_k(const float* __restrict__ hidden,
                                            const float* __restrict__ attn_w,
                                            const float* __restrict__ attn_b,
                                            float* __restrict__ s1) {
  int o = blockIdx.x * 4 + (threadIdx.x >> 6);  // one wave per output, 16384 outputs
  int b = o >> 9, h = o & 511;
  int lane = threadIdx.x & 63;
  const float4* hp = (const float4*)(hidden + (size_t)b * 1024);
  const float4* wp = (const float4*)(attn_w + (size_t)h * 2048);
  float acc = 0.f;
#pragma unroll
  for (int c = 0; c < 4; ++c) {
    float4 a = hp[c * 64 + lane];
    float4 wv = wp[c * 64 + lane];
    acc += a.x * wv.x + a.y * wv.y + a.z * wv.z + a.w * wv.w;
  }
#pragma unroll
  for (int off = 1; off < 64; off <<= 1) acc += __shfl_xor(acc, off);
  if (lane == 0) s1[o] = acc + attn_b[h];
}

// ---- Main fused GEMM: score[b,s] += sum_h tanh(A·B^T + s1) * v ----
// A = eo (fp32, [M=65536][K=1024], staged fp32 via global_load_lds, cvt at frag read)
// B = Bt (f16,  [N=512][K=1024])
__global__ __launch_bounds__(256, 2) void gemm_k(const float* __restrict__ eo,
                                                 const _Float16* __restrict__ Bt,
                                                 const float* __restrict__ s1,
                                                 const float* __restrict__ v,
                                                 float* __restrict__ score) {
  constexpr int BK = 64;
  __shared__ __align__(16) float As[128 * BK];      // 32 KB, row = 256 B
  __shared__ __align__(16) _Float16 Bs[128 * BK];   // 16 KB, row = 128 B

  int bid = blockIdx.x;
  // XCD swizzle: 4 n-tiles of the same m-tile land on the same XCD (share A in L2)
  int x = bid & 7;
  int q = bid >> 3;
  int nt = q & 3;
  int mt = (q >> 2) * 8 + x;           // 0..511

  int tid = threadIdx.x;
  int lane = tid & 63;
  int w = tid >> 6;                    // wave 0..3
  int wm = (w >> 1) * 64;              // wave tile origin (m)
  int wn = (w & 1) * 64;               // wave tile origin (n)

  // Staging source pointers (advance by BK per iteration)
  const float* ga[8];
  const _Float16* gb[4];
#pragma unroll
  for (int ii = 0; ii < 8; ++ii) {
    int iss = w * 8 + ii;                       // A issue 0..31, 4 rows each
    int row = iss * 4 + (lane >> 4);
    ga[ii] = eo + (size_t)(mt * 128 + row) * KDIM + (lane & 15) * 4;
  }
#pragma unroll
  for (int ii = 0; ii < 4; ++ii) {
    int iss = w * 4 + ii;                       // B issue 0..15, 8 rows each
    int row = iss * 8 + (lane >> 3);
    gb[ii] = Bt + (size_t)(nt * 128 + row) * KDIM + (lane & 7) * 8;
  }

  f32x4 acc[4][4];
#pragma unroll
  for (int i = 0; i < 4; ++i)
#pragma unroll
    for (int j = 0; j < 4; ++j) acc[i][j] = (f32x4){0.f, 0.f, 0.f, 0.f};

  int mrow = lane & 15;
  for (int kt = 0; kt < KDIM / BK; ++kt) {
    __syncthreads();   // previous compute done before overwrite
#pragma unroll
    for (int ii = 0; ii < 8; ++ii) {
      gload16(ga[ii], (char*)As + (w * 8 + ii) * 1024);
      ga[ii] += BK;
    }
#pragma unroll
    for (int ii = 0; ii < 4; ++ii) {
      gload16(gb[ii], (char*)Bs + (w * 4 + ii) * 1024);
      gb[ii] += BK;
    }
    __syncthreads();   // vmcnt(0) drain + barrier

#pragma unroll
    for (int kk = 0; kk < 2; ++kk) {
      int qk = kk * 32 + (lane >> 4) * 8;
      f16x8 af[4], bf[4];
#pragma unroll
      for (int i = 0; i < 4; ++i) {
        const float* p = &As[(wm + 16 * i + mrow) * BK + qk];
        float4 a0 = *(const float4*)p;
        float4 a1 = *(const float4*)(p + 4);
        f16x8 t = {(_Float16)a0.x, (_Float16)a0.y, (_Float16)a0.z, (_Float16)a0.w,
                   (_Float16)a1.x, (_Float16)a1.y, (_Float16)a1.z, (_Float16)a1.w};
        af[i] = t;
      }
#pragma unroll
      for (int j = 0; j < 4; ++j)
        bf[j] = *(const f16x8*)&Bs[(wn + 16 * j + mrow) * BK + qk];
#pragma unroll
      for (int i = 0; i < 4; ++i)
#pragma unroll
        for (int j = 0; j < 4; ++j)
          acc[i][j] = __builtin_amdgcn_mfma_f32_16x16x32_f16(af[i], bf[j], acc[i][j], 0, 0, 0);
    }
  }

  // ---- Epilogue: energy = tanh(acc + s1[b][h]); score += energy * v[h] ----
  __syncthreads();
  float* s1s = (float*)As;            // [32][128] fp32 = 16 KB (reuse As)
  float* vsm = (float*)Bs;            // [128] fp32 (reuse Bs)
  for (int t = tid; t < 1024; t += 256) {
    int bb = t >> 5, cc = t & 31;
    ((float4*)s1s)[t] = *(const float4*)(s1 + (size_t)bb * 512 + nt * 128 + cc * 4);
  }
  if (tid < 32) ((float4*)vsm)[tid] = *(const float4*)(v + nt * 128 + tid * 4);
  __syncthreads();

  int quad = lane >> 4;
  int lcol = lane & 15;
  float vv[4];
#pragma unroll
  for (int j = 0; j < 4; ++j) vv[j] = vsm[wn + 16 * j + lcol];

#pragma unroll
  for (int i = 0; i < 4; ++i) {
#pragma unroll
    for (int r = 0; r < 4; ++r) {
      int mloc = wm + 16 * i + 4 * quad + r;
      int bb = mloc & 31;   // mt*128 ≡ 0 (mod 32)
      float sum = 0.f;
#pragma unroll
      for (int j = 0; j < 4; ++j) {
        float e = acc[i][j][r] + s1s[bb * 128 + wn + 16 * j + lcol];
        sum += fast_tanh(e) * vv[j];
      }
      sum += __shfl_xor(sum, 1);
      sum += __shfl_xor(sum, 2);
      sum += __shfl_xor(sum, 4);
      sum += __shfl_xor(sum, 8);
      if (lcol == 0) {
        int mg = mt * 128 + mloc;        // global row m = s*32 + b
        atomicAdd(&score[(mg & 31) * SLEN + (mg >> 5)], sum);
      }
    }
  }
}

// ---- Masked softmax over s for each b; score stored b-major [32][2048] ----
__global__ __launch_bounds__(256) void softmax_k(const float* __restrict__ score,
                                                 const int* __restrict__ mask,
                                                 float* __restrict__ out) {
  int b = blockIdx.x;
  int tid = threadIdx.x;
  int lane = tid & 63, w = tid >> 6;
  __shared__ float red[8];
  float vals[8];
  float mx = -3.4e38f;
#pragma unroll
  for (int i = 0; i < 8; ++i) {
    int s = i * 256 + tid;
    float xv = score[b * SLEN + s];
    if (mask[b * SLEN + s] == 0) xv = -1e10f;
    vals[i] = xv;
    mx = fmaxf(mx, xv);
  }
#pragma unroll
  for (int off = 1; off < 64; off <<= 1) mx = fmaxf(mx, __shfl_xor(mx, off));
  if (lane == 0) red[w] = mx;
  __syncthreads();
  mx = fmaxf(fmaxf(red[0], red[1]), fmaxf(red[2], red[3]));
  float sum = 0.f;
#pragma unroll
  for (int i = 0; i < 8; ++i) {
    vals[i] = __expf(vals[i] - mx);
    sum += vals[i];
  }
#pragma unroll
  for (int off = 1; off < 64; off <<= 1) sum += __shfl_xor(sum, off);
  if (lane == 0) red[4 + w] = sum;
  __syncthreads();
  sum = red[4] + red[5] + red[6] + red[7];
  float inv = 1.0f / sum;
#pragma unroll
  for (int i = 0; i < 8; ++i) out[b * SLEN + i * 256 + tid] = vals[i] * inv;
}

extern "C" void kernel_launch(void* const* d_in, const int* in_sizes, int n_in,
                              void* d_out, int out_size, void* d_ws, size_t ws_size,
                              hipStream_t stream) {
  const float* hidden = (const float*)d_in[0];
  const float* eo     = (const float*)d_in[1];
  const int*   mask   = (const int*)d_in[2];
  const float* attn_w = (const float*)d_in[3];
  const float* attn_b = (const float*)d_in[4];
  const float* v      = (const float*)d_in[5];
  float* out = (float*)d_out;

  char* wsb = (char*)d_ws;
  _Float16* Bt = (_Float16*)wsb;                              // 1 MB
  float* s1    = (float*)(wsb + (1 << 20));                   // 64 KB
  float* score = (float*)(wsb + (1 << 20) + (1 << 16));       // 256 KB

  convB_k<<<512, 256, 0, stream>>>(attn_w, Bt);
  s1_k<<<4096, 256, 0, stream>>>(hidden, attn_w, attn_b, s1);
  hipMemsetAsync(score, 0, BATCH * SLEN * sizeof(float), stream);
  gemm_k<<<2048, 256, 0, stream>>>(eo, Bt, s1, v, score);
  softmax_k<<<BATCH, 256, 0, stream>>>(score, mask, out);
}

// Round 2
// 449.971 us; speedup vs baseline: 1.6241x; 1.6241x over previous
//
#include <hip/hip_runtime.h>

#define SLEN 2048
#define BATCH 32
#define HDIM 512
#define KDIM 1024   // 2H

typedef _Float16 f16x8 __attribute__((ext_vector_type(8)));
typedef _Float16 f16x4 __attribute__((ext_vector_type(4)));
typedef float f32x4 __attribute__((ext_vector_type(4)));

__device__ __forceinline__ void gload16(const void* g, void* l) {
  __builtin_amdgcn_global_load_lds(
      (const __attribute__((address_space(1))) unsigned int*)g,
      (__attribute__((address_space(3))) unsigned int*)l, 16, 0, 0);
}

__device__ __forceinline__ float fast_tanh(float x) {
  float e = __expf(2.0f * x);
  return 1.0f - 2.0f * __builtin_amdgcn_rcpf(e + 1.0f);
}

// ---- prep: blocks [0,512) convert W2->f16; blocks [512,4608) compute s1 ----
__global__ __launch_bounds__(256) void prep_k(const float* __restrict__ attn_w,
                                              const float* __restrict__ attn_b,
                                              const float* __restrict__ hidden,
                                              _Float16* __restrict__ Bt,
                                              float* __restrict__ s1) {
  if (blockIdx.x < 512) {
    int t = blockIdx.x * 256 + threadIdx.x;
    int h = t >> 8;
    int c = t & 255;
    float4 x = *(const float4*)(attn_w + (size_t)h * 2048 + 1024 + c * 4);
    f16x4 y = {(_Float16)x.x, (_Float16)x.y, (_Float16)x.z, (_Float16)x.w};
    *(f16x4*)(Bt + (size_t)h * 1024 + c * 4) = y;
  } else {
    int o = (blockIdx.x - 512) * 4 + (threadIdx.x >> 6);  // one wave per output
    int b = o >> 9, h = o & 511;
    int lane = threadIdx.x & 63;
    const float4* hp = (const float4*)(hidden + (size_t)b * 1024);
    const float4* wp = (const float4*)(attn_w + (size_t)h * 2048);
    float acc = 0.f;
#pragma unroll
    for (int c = 0; c < 4; ++c) {
      float4 a = hp[c * 64 + lane];
      float4 wv = wp[c * 64 + lane];
      acc += a.x * wv.x + a.y * wv.y + a.z * wv.z + a.w * wv.w;
    }
#pragma unroll
    for (int off = 1; off < 64; off <<= 1) acc += __shfl_xor(acc, off);
    if (lane == 0) s1[o] = acc + attn_b[h];
  }
}

// ---- Main fused GEMM with XOR-swizzled LDS (kills 16-way bank conflicts) ----
// A tile As[128][64] fp32: physical 16B-chunk p of row r holds logical chunk p^(r&15)
// B tile Bs[128][64] f16 : physical 16B-chunk p of row r holds logical chunk p^(r&7)
__global__ __launch_bounds__(256, 2) void gemm_k(const float* __restrict__ eo,
                                                 const _Float16* __restrict__ Bt,
                                                 const float* __restrict__ s1,
                                                 const float* __restrict__ v,
                                                 float* __restrict__ score) {
  constexpr int BK = 64;
  __shared__ __align__(16) float As[128 * BK];      // 32 KB
  __shared__ __align__(16) _Float16 Bs[128 * BK];   // 16 KB

  int bid = blockIdx.x;
  // XCD swizzle: 4 n-tiles of the same m-tile on one XCD (share A in its L2)
  int x = bid & 7;
  int q = bid >> 3;
  int nt = q & 3;
  int mt = (q >> 2) * 8 + x;

  int tid = threadIdx.x;
  int lane = tid & 63;
  int w = tid >> 6;
  int wm = (w >> 1) * 64;
  int wn = (w & 1) * 64;

  // Staging source pointers, with per-lane XOR swizzle folded into the source
  // address (LDS dest is fixed: wave-uniform base + lane*16).
  const float* ga[8];
  const _Float16* gb[4];
#pragma unroll
  for (int ii = 0; ii < 8; ++ii) {
    int iss = w * 8 + ii;
    int rloc = iss * 4 + (lane >> 4);                 // row in 0..127
    int sc = (lane & 15) ^ (rloc & 15);               // source float4-chunk
    ga[ii] = eo + (size_t)(mt * 128 + rloc) * KDIM + sc * 4;
  }
#pragma unroll
  for (int ii = 0; ii < 4; ++ii) {
    int iss = w * 4 + ii;
    int rloc = iss * 8 + (lane >> 3);
    int sc = (lane & 7) ^ (rloc & 7);                 // source f16x8-chunk
    gb[ii] = Bt + (size_t)(nt * 128 + rloc) * KDIM + sc * 8;
  }

  f32x4 acc[4][4];
#pragma unroll
  for (int i = 0; i < 4; ++i)
#pragma unroll
    for (int j = 0; j < 4; ++j) acc[i][j] = (f32x4){0.f, 0.f, 0.f, 0.f};

  int mrow = lane & 15;
  int quad = lane >> 4;
  for (int kt = 0; kt < KDIM / BK; ++kt) {
    __syncthreads();
#pragma unroll
    for (int ii = 0; ii < 8; ++ii) {
      gload16(ga[ii], (char*)As + (w * 8 + ii) * 1024);
      ga[ii] += BK;
    }
#pragma unroll
    for (int ii = 0; ii < 4; ++ii) {
      gload16(gb[ii], (char*)Bs + (w * 4 + ii) * 1024);
      gb[ii] += BK;
    }
    __syncthreads();

#pragma unroll
    for (int kk = 0; kk < 2; ++kk) {
      int c0 = kk * 8 + quad * 2;     // logical float4-chunk (A), 4 floats each
      int cB = kk * 4 + quad;         // logical f16x8-chunk (B), 8 halves each
      f16x8 af[4], bf[4];
#pragma unroll
      for (int i = 0; i < 4; ++i) {
        const float* pa = &As[(wm + 16 * i + mrow) * BK];
        float4 a0 = *(const float4*)(pa + ((c0 ^ mrow) << 2));
        float4 a1 = *(const float4*)(pa + (((c0 + 1) ^ mrow) << 2));
        f16x8 t = {(_Float16)a0.x, (_Float16)a0.y, (_Float16)a0.z, (_Float16)a0.w,
                   (_Float16)a1.x, (_Float16)a1.y, (_Float16)a1.z, (_Float16)a1.w};
        af[i] = t;
      }
#pragma unroll
      for (int j = 0; j < 4; ++j)
        bf[j] = *(const f16x8*)&Bs[(wn + 16 * j + mrow) * BK + ((cB ^ (mrow & 7)) << 3)];
#pragma unroll
      for (int i = 0; i < 4; ++i)
#pragma unroll
        for (int j = 0; j < 4; ++j)
          acc[i][j] = __builtin_amdgcn_mfma_f32_16x16x32_f16(af[i], bf[j], acc[i][j], 0, 0, 0);
    }
  }

  // ---- Epilogue: energy = tanh(acc + s1[b][h]); score += energy * v[h] ----
  __syncthreads();
  float* s1s = (float*)As;            // [32][132] fp32 (stride-132 kills 4-way)
  float* vsm = (float*)Bs;            // [128] fp32
  for (int t = tid; t < 1024; t += 256) {
    int bb = t >> 5, cc = t & 31;
    ((float4*)s1s)[bb * 33 + cc] = *(const float4*)(s1 + (size_t)bb * 512 + nt * 128 + cc * 4);
  }
  if (tid < 32) ((float4*)vsm)[tid] = *(const float4*)(v + nt * 128 + tid * 4);
  __syncthreads();

  int lcol = lane & 15;
  float vv[4];
#pragma unroll
  for (int j = 0; j < 4; ++j) vv[j] = vsm[wn + 16 * j + lcol];

#pragma unroll
  for (int i = 0; i < 4; ++i) {
#pragma unroll
    for (int r = 0; r < 4; ++r) {
      int mloc = wm + 16 * i + 4 * quad + r;
      int bb = mloc & 31;   // mt*128 ≡ 0 (mod 32)
      float sum = 0.f;
#pragma unroll
      for (int j = 0; j < 4; ++j) {
        float e = acc[i][j][r] + s1s[bb * 132 + wn + 16 * j + lcol];
        sum += fast_tanh(e) * vv[j];
      }
      sum += __shfl_xor(sum, 1);
      sum += __shfl_xor(sum, 2);
      sum += __shfl_xor(sum, 4);
      sum += __shfl_xor(sum, 8);
      if (lcol == 0) {
        int mg = mt * 128 + mloc;        // global row m = s*32 + b
        atomicAdd(&score[(mg & 31) * SLEN + (mg >> 5)], sum);
      }
    }
  }
}

// ---- Masked softmax over s for each b; score stored b-major [32][2048] ----
__global__ __launch_bounds__(256) void softmax_k(const float* __restrict__ score,
                                                 const int* __restrict__ mask,
                                                 float* __restrict__ out) {
  int b = blockIdx.x;
  int tid = threadIdx.x;
  int lane = tid & 63, w = tid >> 6;
  __shared__ float red[8];
  float vals[8];
  float mx = -3.4e38f;
#pragma unroll
  for (int i = 0; i < 8; ++i) {
    int s = i * 256 + tid;
    float xv = score[b * SLEN + s];
    if (mask[b * SLEN + s] == 0) xv = -1e10f;
    vals[i] = xv;
    mx = fmaxf(mx, xv);
  }
#pragma unroll
  for (int off = 1; off < 64; off <<= 1) mx = fmaxf(mx, __shfl_xor(mx, off));
  if (lane == 0) red[w] = mx;
  __syncthreads();
  mx = fmaxf(fmaxf(red[0], red[1]), fmaxf(red[2], red[3]));
  float sum = 0.f;
#pragma unroll
  for (int i = 0; i < 8; ++i) {
    vals[i] = __expf(vals[i] - mx);
    sum += vals[i];
  }
#pragma unroll
  for (int off = 1; off < 64; off <<= 1) sum += __shfl_xor(sum, off);
  if (lane == 0) red[4 + w] = sum;
  __syncthreads();
  sum = red[4] + red[5] + red[6] + red[7];
  float inv = 1.0f / sum;
#pragma unroll
  for (int i = 0; i < 8; ++i) out[b * SLEN + i * 256 + tid] = vals[i] * inv;
}

extern "C" void kernel_launch(void* const* d_in, const int* in_sizes, int n_in,
                              void* d_out, int out_size, void* d_ws, size_t ws_size,
                              hipStream_t stream) {
  const float* hidden = (const float*)d_in[0];
  const float* eo     = (const float*)d_in[1];
  const int*   mask   = (const int*)d_in[2];
  const float* attn_w = (const float*)d_in[3];
  const float* attn_b = (const float*)d_in[4];
  const float* v      = (const float*)d_in[5];
  float* out = (float*)d_out;

  char* wsb = (char*)d_ws;
  _Float16* Bt = (_Float16*)wsb;                              // 1 MB
  float* s1    = (float*)(wsb + (1 << 20));                   // 64 KB
  float* score = (float*)(wsb + (1 << 20) + (1 << 16));       // 256 KB

  prep_k<<<4608, 256, 0, stream>>>(attn_w, attn_b, hidden, Bt, s1);
  hipMemsetAsync(score, 0, BATCH * SLEN * sizeof(float), stream);
  gemm_k<<<2048, 256, 0, stream>>>(eo, Bt, s1, v, score);
  softmax_k<<<BATCH, 256, 0, stream>>>(score, mask, out);
}

// Round 3
// 443.115 us; speedup vs baseline: 1.6492x; 1.0155x over previous
//
#include <hip/hip_runtime.h>

#define SLEN 2048
#define BATCH 32
#define HDIM 512
#define KDIM 1024   // 2H

typedef _Float16 f16x8 __attribute__((ext_vector_type(8)));
typedef _Float16 f16x4 __attribute__((ext_vector_type(4)));
typedef float f32x4 __attribute__((ext_vector_type(4)));

__device__ __forceinline__ void gload16(const void* g, void* l) {
  __builtin_amdgcn_global_load_lds(
      (const __attribute__((address_space(1))) unsigned int*)g,
      (__attribute__((address_space(3))) unsigned int*)l, 16, 0, 0);
}

__device__ __forceinline__ float fast_tanh(float x) {
  float e = __expf(2.0f * x);
  return 1.0f - 2.0f * __builtin_amdgcn_rcpf(e + 1.0f);
}

// ---- prep: [0,512) W2->f16 | [512,4608) s1 | [4608,4640) zero score ----
__global__ __launch_bounds__(256) void prep_k(const float* __restrict__ attn_w,
                                              const float* __restrict__ attn_b,
                                              const float* __restrict__ hidden,
                                              _Float16* __restrict__ Bt,
                                              float* __restrict__ s1,
                                              float* __restrict__ score) {
  if (blockIdx.x < 512) {
    int t = blockIdx.x * 256 + threadIdx.x;
    int h = t >> 8;
    int c = t & 255;
    float4 x = *(const float4*)(attn_w + (size_t)h * 2048 + 1024 + c * 4);
    f16x4 y = {(_Float16)x.x, (_Float16)x.y, (_Float16)x.z, (_Float16)x.w};
    *(f16x4*)(Bt + (size_t)h * 1024 + c * 4) = y;
  } else if (blockIdx.x < 4608) {
    int o = (blockIdx.x - 512) * 4 + (threadIdx.x >> 6);  // one wave per output
    int b = o >> 9, h = o & 511;
    int lane = threadIdx.x & 63;
    const float4* hp = (const float4*)(hidden + (size_t)b * 1024);
    const float4* wp = (const float4*)(attn_w + (size_t)h * 2048);
    float acc = 0.f;
#pragma unroll
    for (int c = 0; c < 4; ++c) {
      float4 a = hp[c * 64 + lane];
      float4 wv = wp[c * 64 + lane];
      acc += a.x * wv.x + a.y * wv.y + a.z * wv.z + a.w * wv.w;
    }
#pragma unroll
    for (int off = 1; off < 64; off <<= 1) acc += __shfl_xor(acc, off);
    if (lane == 0) s1[o] = acc + attn_b[h];
  } else {
    int idx = (blockIdx.x - 4608) * 256 + threadIdx.x;
    float4 z = {0.f, 0.f, 0.f, 0.f};
    ((float4*)score)[idx] = z;
    ((float4*)score)[idx + 8192] = z;
  }
}

// ---- Main fused GEMM: BM=256, BN=128, BK=64; wave = 64m x 128n ----
// A tile As[256][64] fp32, XOR-swizzled: phys 16B-chunk p of row r = logical p^(r&15)
// B tile Bs[128][64] f16,  XOR-swizzled: phys 16B-chunk p of row r = logical p^(r&7)
__global__ __launch_bounds__(256, 2) void gemm_k(const float* __restrict__ eo,
                                                 const _Float16* __restrict__ Bt,
                                                 const float* __restrict__ s1,
                                                 const float* __restrict__ v,
                                                 float* __restrict__ score) {
  constexpr int BK = 64;
  __shared__ __align__(16) float As[256 * BK];      // 64 KB
  __shared__ __align__(16) _Float16 Bs[128 * BK];   // 16 KB

  int bid = blockIdx.x;
  // XCD swizzle: the 4 n-tiles of one m-tile land on one XCD (share A in its L2)
  int x = bid & 7;
  int q = bid >> 3;
  int nt = q & 3;
  int mt = (q >> 2) * 8 + x;           // 0..255

  int tid = threadIdx.x;
  int lane = tid & 63;
  int w = tid >> 6;
  int wm = w * 64;                     // wave owns rows wm..wm+63, all 128 n

  // Staging pointers. A: issues ii and ii+8 differ by exactly 32 rows (swizzle
  // identical since 32 ≡ 0 mod 16) -> keep 8 ptrs, second half at +32*KDIM.
  const float* ga[8];
  const _Float16* gb[4];
#pragma unroll
  for (int ii = 0; ii < 8; ++ii) {
    int iss = w * 16 + ii;
    int rloc = iss * 4 + (lane >> 4);                 // row in 0..127 (first half)
    int sc = (lane & 15) ^ (rloc & 15);               // source float4-chunk
    ga[ii] = eo + (size_t)(mt * 256 + rloc) * KDIM + sc * 4;
  }
#pragma unroll
  for (int ii = 0; ii < 4; ++ii) {
    int iss = w * 4 + ii;
    int rloc = iss * 8 + (lane >> 3);
    int sc = (lane & 7) ^ (rloc & 7);                 // source f16x8-chunk
    gb[ii] = Bt + (size_t)(nt * 128 + rloc) * KDIM + sc * 8;
  }

  f32x4 acc[4][8];
#pragma unroll
  for (int i = 0; i < 4; ++i)
#pragma unroll
    for (int j = 0; j < 8; ++j) acc[i][j] = (f32x4){0.f, 0.f, 0.f, 0.f};

  int mrow = lane & 15;
  int quad = lane >> 4;
  for (int kt = 0; kt < KDIM / BK; ++kt) {
    __syncthreads();
#pragma unroll
    for (int ii = 0; ii < 8; ++ii) {
      gload16(ga[ii], (char*)As + (w * 16 + ii) * 1024);
      gload16(ga[ii] + 32 * KDIM, (char*)As + (w * 16 + ii + 8) * 1024);
      ga[ii] += BK;
    }
#pragma unroll
    for (int ii = 0; ii < 4; ++ii) {
      gload16(gb[ii], (char*)Bs + (w * 4 + ii) * 1024);
      gb[ii] += BK;
    }
    __syncthreads();

#pragma unroll
    for (int kk = 0; kk < 2; ++kk) {
      int c0 = kk * 8 + quad * 2;     // logical float4-chunk (A)
      int cB = kk * 4 + quad;         // logical f16x8-chunk (B)
      f16x8 af[4], bf[8];
#pragma unroll
      for (int j = 0; j < 8; ++j)
        bf[j] = *(const f16x8*)&Bs[(16 * j + mrow) * BK + ((cB ^ (mrow & 7)) << 3)];
#pragma unroll
      for (int i = 0; i < 4; ++i) {
        const float* pa = &As[(wm + 16 * i + mrow) * BK];
        float4 a0 = *(const float4*)(pa + ((c0 ^ mrow) << 2));
        float4 a1 = *(const float4*)(pa + (((c0 + 1) ^ mrow) << 2));
        f16x8 t = {(_Float16)a0.x, (_Float16)a0.y, (_Float16)a0.z, (_Float16)a0.w,
                   (_Float16)a1.x, (_Float16)a1.y, (_Float16)a1.z, (_Float16)a1.w};
        af[i] = t;
      }
#pragma unroll
      for (int i = 0; i < 4; ++i)
#pragma unroll
        for (int j = 0; j < 8; ++j)
          acc[i][j] = __builtin_amdgcn_mfma_f32_16x16x32_f16(af[i], bf[j], acc[i][j], 0, 0, 0);
    }
  }

  // ---- Epilogue: energy = tanh(acc + s1[b][h]); score += energy * v[h] ----
  __syncthreads();
  float* s1s = (float*)As;            // [32][132] fp32 (stride-132: conflict-free)
  float* vsm = (float*)Bs;            // [128] fp32
  for (int t = tid; t < 1024; t += 256) {
    int bb = t >> 5, cc = t & 31;
    ((float4*)s1s)[bb * 33 + cc] = *(const float4*)(s1 + (size_t)bb * 512 + nt * 128 + cc * 4);
  }
  if (tid < 32) ((float4*)vsm)[tid] = *(const float4*)(v + nt * 128 + tid * 4);
  __syncthreads();

  int lcol = lane & 15;
  float vv[8];
#pragma unroll
  for (int j = 0; j < 8; ++j) vv[j] = vsm[16 * j + lcol];

#pragma unroll
  for (int i = 0; i < 4; ++i) {
#pragma unroll
    for (int r = 0; r < 4; ++r) {
      int mloc = wm + 16 * i + 4 * quad + r;
      int bb = mloc & 31;   // mt*256 ≡ 0 (mod 32)
      float sum = 0.f;
#pragma unroll
      for (int j = 0; j < 8; ++j) {
        float e = acc[i][j][r] + s1s[bb * 132 + 16 * j + lcol];
        sum += fast_tanh(e) * vv[j];
      }
      sum += __shfl_xor(sum, 1);
      sum += __shfl_xor(sum, 2);
      sum += __shfl_xor(sum, 4);
      sum += __shfl_xor(sum, 8);
      if (lcol == 0) {
        int mg = mt * 256 + mloc;        // global row m = s*32 + b
        atomicAdd(&score[(mg & 31) * SLEN + (mg >> 5)], sum);
      }
    }
  }
}

// ---- Masked softmax over s for each b; score stored b-major [32][2048] ----
__global__ __launch_bounds__(256) void softmax_k(const float* __restrict__ score,
                                                 const int* __restrict__ mask,
                                                 float* __restrict__ out) {
  int b = blockIdx.x;
  int tid = threadIdx.x;
  int lane = tid & 63, w = tid >> 6;
  __shared__ float red[8];
  float vals[8];
  float mx = -3.4e38f;
#pragma unroll
  for (int i = 0; i < 8; ++i) {
    int s = i * 256 + tid;
    float xv = score[b * SLEN + s];
    if (mask[b * SLEN + s] == 0) xv = -1e10f;
    vals[i] = xv;
    mx = fmaxf(mx, xv);
  }
#pragma unroll
  for (int off = 1; off < 64; off <<= 1) mx = fmaxf(mx, __shfl_xor(mx, off));
  if (lane == 0) red[w] = mx;
  __syncthreads();
  mx = fmaxf(fmaxf(red[0], red[1]), fmaxf(red[2], red[3]));
  float sum = 0.f;
#pragma unroll
  for (int i = 0; i < 8; ++i) {
    vals[i] = __expf(vals[i] - mx);
    sum += vals[i];
  }
#pragma unroll
  for (int off = 1; off < 64; off <<= 1) sum += __shfl_xor(sum, off);
  if (lane == 0) red[4 + w] = sum;
  __syncthreads();
  sum = red[4] + red[5] + red[6] + red[7];
  float inv = 1.0f / sum;
#pragma unroll
  for (int i = 0; i < 8; ++i) out[b * SLEN + i * 256 + tid] = vals[i] * inv;
}

extern "C" void kernel_launch(void* const* d_in, const int* in_sizes, int n_in,
                              void* d_out, int out_size, void* d_ws, size_t ws_size,
                              hipStream_t stream) {
  const float* hidden = (const float*)d_in[0];
  const float* eo     = (const float*)d_in[1];
  const int*   mask   = (const int*)d_in[2];
  const float* attn_w = (const float*)d_in[3];
  const float* attn_b = (const float*)d_in[4];
  const float* v      = (const float*)d_in[5];
  float* out = (float*)d_out;

  char* wsb = (char*)d_ws;
  _Float16* Bt = (_Float16*)wsb;                              // 1 MB
  float* s1    = (float*)(wsb + (1 << 20));                   // 64 KB
  float* score = (float*)(wsb + (1 << 20) + (1 << 16));       // 256 KB

  prep_k<<<4640, 256, 0, stream>>>(attn_w, attn_b, hidden, Bt, s1, score);
  gemm_k<<<1024, 256, 0, stream>>>(eo, Bt, s1, v, score);
  softmax_k<<<BATCH, 256, 0, stream>>>(score, mask, out);
}